// Round 1
// baseline (12247.430 us; speedup 1.0000x reference)
//
#include <hip/hip_runtime.h>
#include <math.h>

#define NTH 1024
#define SD 128
#define OD 64
#define PST 130   // row stride for 128-wide matrices in LDS
#define SST 65    // row stride for 64-wide matrices in LDS

// LDS float offsets
#define OFF_P     0            // [128][130] P / P_pred / P_u ; frozen: rows 0..127 = A
#define OFF_T     16640        // [128][130] X temp ; later PCtT [64][130]; frozen: rows 128..191 = C@A
#define OFF_PCTT  16640        // [64][130]  (C @ P_pred)
#define OFF_S     24960        // [64][65] S (destroyed by chol); later Linv
#define OFF_L     29120        // [64][65] L
#define OFF_LINV  24960
#define OFF_KT    24960        // [64][130] K^T (overwrites Linv+L)
#define OFF_SINV  33280        // [64][65]
#define OFF_Z     37440        // 128
#define OFF_T1    37568        // 192  (pre-freeze: z_pred in first 128)
#define OFF_INNOV 37760        // 64
#define OFF_RED   37824        // 64
#define OFF_MISC  37888        // [0]=frozen flag [1]=hasNaN [2]=valid
#define LDS_FLOATS 37896

#define LOG2PI_F 1.8378770664093453f
#define FREEZE_TOL 1e-5f

__launch_bounds__(NTH)
__global__ void kf_seq(const float* __restrict__ y, const float* __restrict__ A,
                       const float* __restrict__ C, const float* __restrict__ Q,
                       const float* __restrict__ R, const float* __restrict__ z0,
                       const float* __restrict__ P0, float* __restrict__ out,
                       int T, int* __restrict__ ws_tf) {
  extern __shared__ float lds[];
  const int tid = (int)threadIdx.x;
  const int ti = tid >> 5, tj = tid & 31;
  float* states = out;
  float* cov = out + (size_t)T * SD;

  // ---- init: P <- P0, z <- z0 ----
  for (int p = 0; p < 16; ++p) {
    int idx = tid + p * NTH;
    lds[OFF_P + (idx >> 7) * PST + (idx & 127)] = P0[idx];
  }
  if (tid < SD) lds[OFF_Z + tid] = z0[tid];
  if (tid == 0) { lds[OFF_MISC + 0] = 0.f; lds[OFF_MISC + 1] = 0.f; }
  __syncthreads();

  // ---- global NaN scan of y (decides whether freezing is allowed) ----
  {
    int bad = 0;
    int n4 = (T * OD) >> 2;
    for (int idx = tid; idx < n4; idx += NTH) {
      float4 v = ((const float4*)y)[idx];
      if (v.x != v.x || v.y != v.y || v.z != v.z || v.w != v.w) bad = 1;
    }
    if (bad) lds[OFF_MISC + 1] = 1.f;
  }
  __syncthreads();
  const bool hasNaN = (lds[OFF_MISC + 1] != 0.f);

  float llacc = 0.f;      // thread 0
  float logdet_cur = 0.f; // thread 0
  int tF = T;

  for (int t = 0; t < T; ++t) {
    if (t > 0) {
      // ---- X = A @ P  (X[i][j] = sum_k A[i][k] P[k][j]) ----
      {
        const int i0 = ti * 4, j0 = tj * 4;
        float acc[4][4] = {};
        for (int k = 0; k < SD; ++k) {
          float av[4], bv[4];
#pragma unroll
          for (int r = 0; r < 4; ++r) av[r] = A[(i0 + r) * SD + k];
#pragma unroll
          for (int c = 0; c < 4; ++c) bv[c] = lds[OFF_P + k * PST + j0 + c];
#pragma unroll
          for (int r = 0; r < 4; ++r)
#pragma unroll
            for (int c = 0; c < 4; ++c) acc[r][c] += av[r] * bv[c];
        }
        __syncthreads();  // all reads of P done before anything else
#pragma unroll
        for (int r = 0; r < 4; ++r)
#pragma unroll
          for (int c = 0; c < 4; ++c)
            lds[OFF_T + (i0 + r) * PST + j0 + c] = acc[r][c];
      }
      __syncthreads();
      // ---- P_pred = A @ X^T + Q  (uses symmetry of A P A^T) ----
      {
        const int i0 = ti * 4, j0 = tj * 4;
        float acc[4][4] = {};
        for (int k = 0; k < SD; ++k) {
          float av[4], xv[4];
#pragma unroll
          for (int r = 0; r < 4; ++r) av[r] = A[(i0 + r) * SD + k];
#pragma unroll
          for (int c = 0; c < 4; ++c) xv[c] = lds[OFF_T + (j0 + c) * PST + k];
#pragma unroll
          for (int r = 0; r < 4; ++r)
#pragma unroll
            for (int c = 0; c < 4; ++c) acc[r][c] += av[r] * xv[c];
        }
#pragma unroll
        for (int r = 0; r < 4; ++r)
#pragma unroll
          for (int c = 0; c < 4; ++c)
            lds[OFF_P + (i0 + r) * PST + j0 + c] =
                acc[r][c] + Q[(i0 + r) * SD + j0 + c];
      }
      // ---- z_pred = A @ z  (independent of P_pred writes) ----
      {
        int i = tid >> 3, s = tid & 7;
        float sum = 0.f;
        for (int kk = 0; kk < 16; ++kk) {
          int k = s * 16 + kk;
          sum += A[i * SD + k] * lds[OFF_Z + k];
        }
        sum += __shfl_xor(sum, 1);
        sum += __shfl_xor(sum, 2);
        sum += __shfl_xor(sum, 4);
        if (s == 0) lds[OFF_T1 + i] = sum;
      }
      if (tid == 0) lds[OFF_MISC + 2] = 1.f;
      __syncthreads();
    } else {
      if (tid < SD) lds[OFF_T1 + tid] = lds[OFF_Z + tid];
      if (tid == 0) lds[OFF_MISC + 2] = 1.f;
      __syncthreads();
    }

    // ---- PCtT = C @ P_pred  [64][128];  + per-step NaN check ----
    {
      const int a0 = ti * 2, i0 = tj * 4;
      float acc[2][4] = {};
      for (int m = 0; m < SD; ++m) {
        float c0 = C[(a0 + 0) * SD + m];
        float c1 = C[(a0 + 1) * SD + m];
        float pv[4];
#pragma unroll
        for (int c = 0; c < 4; ++c) pv[c] = lds[OFF_P + m * PST + i0 + c];
#pragma unroll
        for (int c = 0; c < 4; ++c) { acc[0][c] += c0 * pv[c]; acc[1][c] += c1 * pv[c]; }
      }
#pragma unroll
      for (int r = 0; r < 2; ++r)
#pragma unroll
        for (int c = 0; c < 4; ++c)
          lds[OFF_PCTT + (a0 + r) * PST + i0 + c] = acc[r][c];
      if (tid < OD) {
        float yv = y[(size_t)t * OD + tid];
        if (yv != yv) lds[OFF_MISC + 2] = 0.f;
      }
    }
    __syncthreads();

    // ---- S = C P_pred C^T + R + jit : S[a][b] = sum_k C[a][k]*PCtT[b][k] ----
    {
      const int a0 = ti * 2, b0 = tj * 2;
      float acc[2][2] = {};
      for (int k = 0; k < SD; ++k) {
        float c0 = C[(a0 + 0) * SD + k];
        float c1 = C[(a0 + 1) * SD + k];
        float p0 = lds[OFF_PCTT + (b0 + 0) * PST + k];
        float p1 = lds[OFF_PCTT + (b0 + 1) * PST + k];
        acc[0][0] += c0 * p0; acc[0][1] += c0 * p1;
        acc[1][0] += c1 * p0; acc[1][1] += c1 * p1;
      }
#pragma unroll
      for (int r = 0; r < 2; ++r)
#pragma unroll
        for (int c = 0; c < 2; ++c) {
          int a = a0 + r, b = b0 + c;
          lds[OFF_S + a * SST + b] =
              acc[r][c] + R[a * OD + b] + ((a == b) ? 1e-6f : 0.f);
        }
    }
    // ---- innov = y_safe - C z_pred (threads 0..511) ----
    if (tid < 512) {
      int o = tid >> 3, s = tid & 7;
      float sum = 0.f;
      for (int kk = 0; kk < 16; ++kk) {
        int k = s * 16 + kk;
        sum += C[o * SD + k] * lds[OFF_T1 + k];
      }
      sum += __shfl_xor(sum, 1);
      sum += __shfl_xor(sum, 2);
      sum += __shfl_xor(sum, 4);
      if (s == 0) {
        float yv = y[(size_t)t * OD + o];
        if (yv != yv) yv = 0.f;
        lds[OFF_INNOV + o] = yv - sum;
      }
    }
    __syncthreads();

    // ---- Cholesky S = L L^T (right-looking, L separate), logdet ----
    float logdet_step = 0.f;
    for (int j = 0; j < OD; ++j) {
      float a = lds[OFF_S + j * SST + j];
      float inva = 1.0f / a;
      float irs = rsqrtf(a);
      if (tid == 0) logdet_step += logf(a);
#pragma unroll
      for (int p = 0; p < 4; ++p) {
        int idx = tid + p * NTH;
        int i = idx >> 6, k = idx & 63;
        if (i > j && k > j)
          lds[OFF_S + i * SST + k] -=
              lds[OFF_S + i * SST + j] * lds[OFF_S + k * SST + j] * inva;
        if (k == j && i >= j)
          lds[OFF_L + i * SST + j] = lds[OFF_S + i * SST + j] * irs;
      }
      __syncthreads();
    }
    if (tid == 0) logdet_cur = logdet_step;

    // ---- Linv (64 threads, column each), overwrites S region ----
    if (tid < OD) {
      int c = tid;
      for (int i = 0; i < c; ++i) lds[OFF_LINV + i * SST + c] = 0.f;
      for (int i = c; i < OD; ++i) {
        float s = (i == c) ? 1.f : 0.f;
        for (int j = c; j < i; ++j)
          s -= lds[OFF_L + i * SST + j] * lds[OFF_LINV + j * SST + c];
        lds[OFF_LINV + i * SST + c] = s / lds[OFF_L + i * SST + i];
      }
    }
    __syncthreads();

    // ---- Sinv = Linv^T Linv ----
    {
      const int a0 = ti * 2, b0 = tj * 2;
      float acc[2][2] = {};
      for (int k = 0; k < OD; ++k) {
        float la0 = lds[OFF_LINV + k * SST + a0 + 0];
        float la1 = lds[OFF_LINV + k * SST + a0 + 1];
        float lb0 = lds[OFF_LINV + k * SST + b0 + 0];
        float lb1 = lds[OFF_LINV + k * SST + b0 + 1];
        acc[0][0] += la0 * lb0; acc[0][1] += la0 * lb1;
        acc[1][0] += la1 * lb0; acc[1][1] += la1 * lb1;
      }
#pragma unroll
      for (int r = 0; r < 2; ++r)
#pragma unroll
        for (int c = 0; c < 2; ++c)
          lds[OFF_SINV + (a0 + r) * SST + b0 + c] = acc[r][c];
    }
    __syncthreads();

    // ---- quad partials (threads<512) and KT = Sinv @ PCtT (all) ----
    if (tid < 512) {
      int o = tid >> 3, s = tid & 7;
      float sum = 0.f;
      for (int kk = 0; kk < 8; ++kk) {
        int k = s * 8 + kk;
        sum += lds[OFF_SINV + o * SST + k] * lds[OFF_INNOV + k];
      }
      sum += __shfl_xor(sum, 1);
      sum += __shfl_xor(sum, 2);
      sum += __shfl_xor(sum, 4);
      if (s == 0) lds[OFF_RED + o] = sum * lds[OFF_INNOV + o];
    }
    {
      const int a0 = ti * 2, i0 = tj * 4;
      float acc[2][4] = {};
      for (int b = 0; b < OD; ++b) {
        float s0 = lds[OFF_SINV + (a0 + 0) * SST + b];
        float s1 = lds[OFF_SINV + (a0 + 1) * SST + b];
        float pv[4];
#pragma unroll
        for (int c = 0; c < 4; ++c) pv[c] = lds[OFF_PCTT + b * PST + i0 + c];
#pragma unroll
        for (int c = 0; c < 4; ++c) { acc[0][c] += s0 * pv[c]; acc[1][c] += s1 * pv[c]; }
      }
      __syncthreads();  // Linv region reads done (Sinv built) -> safe to overwrite with KT
#pragma unroll
      for (int r = 0; r < 2; ++r)
#pragma unroll
        for (int c = 0; c < 4; ++c)
          lds[OFF_KT + (a0 + r) * PST + i0 + c] = acc[r][c];
    }
    __syncthreads();

    const bool valid = (lds[OFF_MISC + 2] != 0.f);
    // ---- ll increment (wave 0) ----
    if (tid < 64) {
      float q = lds[OFF_RED + tid];
      q += __shfl_xor(q, 1);  q += __shfl_xor(q, 2);  q += __shfl_xor(q, 4);
      q += __shfl_xor(q, 8);  q += __shfl_xor(q, 16); q += __shfl_xor(q, 32);
      if (tid == 0 && valid)
        llacc += -0.5f * (logdet_step + q + OD * LOG2PI_F);
    }
    // ---- z update ----
    {
      int i = tid >> 3, s = tid & 7;
      float sum = 0.f;
      for (int kk = 0; kk < 8; ++kk) {
        int k = s * 8 + kk;
        sum += lds[OFF_KT + k * PST + i] * lds[OFF_INNOV + k];
      }
      sum += __shfl_xor(sum, 1);
      sum += __shfl_xor(sum, 2);
      sum += __shfl_xor(sum, 4);
      if (s == 0) {
        float zi = lds[OFF_T1 + i] + (valid ? sum : 0.f);
        lds[OFF_Z + i] = zi;
        states[(size_t)t * SD + i] = zi;
      }
    }
    // ---- P_u = P_pred - K C P_pred  (in place) ----
    {
      const int i0 = ti * 4, j0 = tj * 4;
      float acc[4][4] = {};
      for (int a = 0; a < OD; ++a) {
        float kv[4], pv[4];
#pragma unroll
        for (int r = 0; r < 4; ++r) kv[r] = lds[OFF_KT + a * PST + i0 + r];
#pragma unroll
        for (int c = 0; c < 4; ++c) pv[c] = lds[OFF_PCTT + a * PST + j0 + c];
#pragma unroll
        for (int r = 0; r < 4; ++r)
#pragma unroll
          for (int c = 0; c < 4; ++c) acc[r][c] += kv[r] * pv[c];
      }
      if (valid) {
#pragma unroll
        for (int r = 0; r < 4; ++r)
#pragma unroll
          for (int c = 0; c < 4; ++c)
            lds[OFF_P + (i0 + r) * PST + j0 + c] -= acc[r][c];
      }
    }
    __syncthreads();

    // ---- write cov[t], convergence check vs cov[t-1] ----
    {
      float maxd = 0.f;
      float* covt = cov + (size_t)t * SD * SD;
      const float* covp = cov + (size_t)(t - 1) * SD * SD;
#pragma unroll
      for (int p = 0; p < 4; ++p) {
        int idx = tid + p * NTH;
        int base = idx * 4;
        int i = base >> 7, j = base & 127;
        float v0 = lds[OFF_P + i * PST + j + 0];
        float v1 = lds[OFF_P + i * PST + j + 1];
        float v2 = lds[OFF_P + i * PST + j + 2];
        float v3 = lds[OFF_P + i * PST + j + 3];
        covt[base + 0] = v0; covt[base + 1] = v1;
        covt[base + 2] = v2; covt[base + 3] = v3;
        if (t > 0 && !hasNaN) {
          float4 pv = ((const float4*)covp)[idx];
          maxd = fmaxf(maxd, fmaxf(fmaxf(fabsf(v0 - pv.x), fabsf(v1 - pv.y)),
                                   fmaxf(fabsf(v2 - pv.z), fabsf(v3 - pv.w))));
        }
      }
      for (int m = 1; m < 64; m <<= 1) maxd = fmaxf(maxd, __shfl_xor(maxd, m));
      if ((tid & 63) == 0) lds[OFF_RED + (tid >> 6)] = maxd;
    }
    __syncthreads();
    if (tid == 0) {
      float md = 0.f;
      for (int w = 0; w < 16; ++w) md = fmaxf(md, lds[OFF_RED + w]);
      if (t > 0 && !hasNaN && md < FREEZE_TOL) lds[OFF_MISC + 0] = 1.f;
    }
    __syncthreads();
    if (lds[OFF_MISC + 0] != 0.f) { tF = t + 1; break; }
    __syncthreads();
  }

  // ================= frozen steady-state phase =================
  if (tF < T) {
    // G rows 0..127 = A
    for (int p = 0; p < 16; ++p) {
      int idx = tid + p * NTH;
      lds[OFF_P + (idx >> 7) * PST + (idx & 127)] = A[idx];
    }
    __syncthreads();
    // G rows 128..191 = C @ A
    {
      const int a0 = ti * 2, k0 = tj * 4;
      float acc[2][4] = {};
      for (int m = 0; m < SD; ++m) {
        float c0 = C[(a0 + 0) * SD + m];
        float c1 = C[(a0 + 1) * SD + m];
        float av[4];
#pragma unroll
        for (int c = 0; c < 4; ++c) av[c] = lds[OFF_P + m * PST + k0 + c];
#pragma unroll
        for (int c = 0; c < 4; ++c) { acc[0][c] += c0 * av[c]; acc[1][c] += c1 * av[c]; }
      }
      __syncthreads();
#pragma unroll
      for (int r = 0; r < 2; ++r)
#pragma unroll
        for (int c = 0; c < 4; ++c)
          lds[OFF_P + (SD + a0 + r) * PST + k0 + c] = acc[r][c];
    }
    __syncthreads();

    for (int t2 = tF; t2 < T; ++t2) {
      // P1: t1[r] = G[r] . z  (r<128: A z, r>=128: CA z); stage y
      if (tid < 768) {
        int r = tid >> 2, s = tid & 3;
        float sum = 0.f;
        for (int kk = 0; kk < 32; ++kk) {
          int k = s * 32 + kk;
          sum += lds[OFF_P + r * PST + k] * lds[OFF_Z + k];
        }
        sum += __shfl_xor(sum, 1);
        sum += __shfl_xor(sum, 2);
        if (s == 0) lds[OFF_T1 + r] = sum;
      } else if (tid < 832) {
        int o = tid - 768;
        lds[OFF_INNOV + o] = y[(size_t)t2 * OD + o];
      }
      __syncthreads();
      // P2: z[i] = t1[i] + sum_k KT[k][i]*(y_k - t1[128+k])
      {
        int i = tid >> 3, s = tid & 7;
        float sum = 0.f;
        for (int kk = 0; kk < 8; ++kk) {
          int k = s * 8 + kk;
          float iv = lds[OFF_INNOV + k] - lds[OFF_T1 + SD + k];
          sum += lds[OFF_KT + k * PST + i] * iv;
        }
        sum += __shfl_xor(sum, 1);
        sum += __shfl_xor(sum, 2);
        sum += __shfl_xor(sum, 4);
        if (s == 0) {
          float zi = lds[OFF_T1 + i] + sum;
          lds[OFF_Z + i] = zi;
          states[(size_t)t2 * SD + i] = zi;
        }
      }
      // P3: quad partials
      if (tid < 512) {
        int o = tid >> 3, s = tid & 7;
        float sum = 0.f;
        for (int kk = 0; kk < 8; ++kk) {
          int k = s * 8 + kk;
          float iv = lds[OFF_INNOV + k] - lds[OFF_T1 + SD + k];
          sum += lds[OFF_SINV + o * SST + k] * iv;
        }
        sum += __shfl_xor(sum, 1);
        sum += __shfl_xor(sum, 2);
        sum += __shfl_xor(sum, 4);
        if (s == 0) {
          float ivo = lds[OFF_INNOV + o] - lds[OFF_T1 + SD + o];
          lds[OFF_RED + o] = sum * ivo;
        }
      }
      __syncthreads();
      if (tid < 64) {
        float q = lds[OFF_RED + tid];
        q += __shfl_xor(q, 1);  q += __shfl_xor(q, 2);  q += __shfl_xor(q, 4);
        q += __shfl_xor(q, 8);  q += __shfl_xor(q, 16); q += __shfl_xor(q, 32);
        if (tid == 0) llacc += -0.5f * (logdet_cur + q + OD * LOG2PI_F);
      }
      __syncthreads();
    }
  }

  if (tid == 0) {
    out[(size_t)T * SD + (size_t)T * SD * SD] = llacc;
    ws_tf[0] = tF;
  }
}

// fill cov[t] for t >= tF with steady covariance cov[tF-1]
__global__ void kf_fill(float* __restrict__ cov, const int* __restrict__ ws_tf, int T) {
  int t = (int)blockIdx.x;
  int tF = ws_tf[0];
  if (t < tF) return;
  const float4* src = (const float4*)(cov + (size_t)(tF - 1) * SD * SD);
  float4* dst = (float4*)(cov + (size_t)t * SD * SD);
#pragma unroll
  for (int p = 0; p < 16; ++p) {
    int idx = (int)threadIdx.x + p * 256;
    dst[idx] = src[idx];
  }
}

extern "C" void kernel_launch(void* const* d_in, const int* in_sizes, int n_in,
                              void* d_out, int out_size, void* d_ws, size_t ws_size,
                              hipStream_t stream) {
  const float* y  = (const float*)d_in[0];
  const float* A  = (const float*)d_in[1];
  const float* C  = (const float*)d_in[2];
  const float* Q  = (const float*)d_in[3];
  const float* R  = (const float*)d_in[4];
  const float* z0 = (const float*)d_in[5];
  const float* P0 = (const float*)d_in[6];
  float* out = (float*)d_out;
  int T = in_sizes[0] / OD;
  int* ws_tf = (int*)d_ws;

  size_t ldsBytes = (size_t)LDS_FLOATS * sizeof(float);
  (void)hipFuncSetAttribute((const void*)kf_seq,
                            hipFuncAttributeMaxDynamicSharedMemorySize,
                            (int)ldsBytes);

  kf_seq<<<dim3(1), dim3(NTH), ldsBytes, stream>>>(y, A, C, Q, R, z0, P0, out, T, ws_tf);
  float* cov = out + (size_t)T * SD;
  kf_fill<<<dim3(T), dim3(256), 0, stream>>>(cov, ws_tf, T);
}

// Round 2
// 3798.095 us; speedup vs baseline: 3.2246x; 3.2246x over previous
//
#include <hip/hip_runtime.h>
#include <math.h>

#define NTH 1024
#define SD 128
#define OD 64
#define PST 130   // row stride for 128-wide matrices in LDS
#define SST 65    // row stride for 64-wide matrices in LDS

// LDS float offsets (kf_seq)
#define OFF_P     0            // [128][130] P / P_pred / P_u ; export: A
#define OFF_T     16640        // [128][130] X temp ; later PCtT [64][130]
#define OFF_PCTT  16640        // [64][130]  (C @ P_pred)
#define OFF_S     24960        // [64][65] S (destroyed by chol); later Linv
#define OFF_L     29120        // [64][65] L
#define OFF_LINV  24960
#define OFF_KT    24960        // [64][130] K^T (overwrites Linv+L)
#define OFF_SINV  33280        // [64][65]
#define OFF_Z     37440        // 128
#define OFF_T1    37568        // 192
#define OFF_INNOV 37760        // 64
#define OFF_RED   37824        // 64
#define OFF_MISC  37888        // [0]=frozen flag [1]=hasNaN [2]=valid
#define LDS_FLOATS 37896

// ws float offsets
#define WS_LL    1
#define WS_LOGD  2
#define WS_Z     128
#define WS_KT    1024        // [64][128]  KT[a][i] = K[i][a]
#define WS_SINV  10240       // [64][64]
#define WS_CA    16384       // [64][128]
#define WS_QUAD  24576       // [64] chunk partial quad sums

#define LCH  32              // chunk length (time steps owned per block)
#define WARM 160             // warm-up steps (contraction ~0.9^160 < 1e-7)

#define LOG2PI_F 1.8378770664093453f
#define FREEZE_TOL 1e-5f

__launch_bounds__(NTH)
__global__ void kf_seq(const float* __restrict__ y, const float* __restrict__ A,
                       const float* __restrict__ C, const float* __restrict__ Q,
                       const float* __restrict__ R, const float* __restrict__ z0,
                       const float* __restrict__ P0, float* __restrict__ out,
                       int T, float* __restrict__ wsf, int* __restrict__ wsi) {
  extern __shared__ float lds[];
  const int tid = (int)threadIdx.x;
  const int ti = tid >> 5, tj = tid & 31;
  float* states = out;
  float* cov = out + (size_t)T * SD;

  // ---- init: P <- P0, z <- z0 ----
  for (int p = 0; p < 16; ++p) {
    int idx = tid + p * NTH;
    lds[OFF_P + (idx >> 7) * PST + (idx & 127)] = P0[idx];
  }
  if (tid < SD) lds[OFF_Z + tid] = z0[tid];
  if (tid == 0) { lds[OFF_MISC + 0] = 0.f; lds[OFF_MISC + 1] = 0.f; }
  __syncthreads();

  // ---- global NaN scan of y (decides whether freezing is allowed) ----
  {
    int bad = 0;
    int n4 = (T * OD) >> 2;
    for (int idx = tid; idx < n4; idx += NTH) {
      float4 v = ((const float4*)y)[idx];
      if (v.x != v.x || v.y != v.y || v.z != v.z || v.w != v.w) bad = 1;
    }
    if (bad) lds[OFF_MISC + 1] = 1.f;
  }
  __syncthreads();
  const bool hasNaN = (lds[OFF_MISC + 1] != 0.f);

  float llacc = 0.f;      // thread 0
  float logdet_cur = 0.f; // thread 0
  int tF = T;

  for (int t = 0; t < T; ++t) {
    if (t > 0) {
      // ---- X = A @ P ----
      {
        const int i0 = ti * 4, j0 = tj * 4;
        float acc[4][4] = {};
        for (int k = 0; k < SD; ++k) {
          float av[4], bv[4];
#pragma unroll
          for (int r = 0; r < 4; ++r) av[r] = A[(i0 + r) * SD + k];
#pragma unroll
          for (int c = 0; c < 4; ++c) bv[c] = lds[OFF_P + k * PST + j0 + c];
#pragma unroll
          for (int r = 0; r < 4; ++r)
#pragma unroll
            for (int c = 0; c < 4; ++c) acc[r][c] += av[r] * bv[c];
        }
        __syncthreads();
#pragma unroll
        for (int r = 0; r < 4; ++r)
#pragma unroll
          for (int c = 0; c < 4; ++c)
            lds[OFF_T + (i0 + r) * PST + j0 + c] = acc[r][c];
      }
      __syncthreads();
      // ---- P_pred = A @ X^T + Q ----
      {
        const int i0 = ti * 4, j0 = tj * 4;
        float acc[4][4] = {};
        for (int k = 0; k < SD; ++k) {
          float av[4], xv[4];
#pragma unroll
          for (int r = 0; r < 4; ++r) av[r] = A[(i0 + r) * SD + k];
#pragma unroll
          for (int c = 0; c < 4; ++c) xv[c] = lds[OFF_T + (j0 + c) * PST + k];
#pragma unroll
          for (int r = 0; r < 4; ++r)
#pragma unroll
            for (int c = 0; c < 4; ++c) acc[r][c] += av[r] * xv[c];
        }
#pragma unroll
        for (int r = 0; r < 4; ++r)
#pragma unroll
          for (int c = 0; c < 4; ++c)
            lds[OFF_P + (i0 + r) * PST + j0 + c] =
                acc[r][c] + Q[(i0 + r) * SD + j0 + c];
      }
      // ---- z_pred = A @ z ----
      {
        int i = tid >> 3, s = tid & 7;
        float sum = 0.f;
        for (int kk = 0; kk < 16; ++kk) {
          int k = s * 16 + kk;
          sum += A[i * SD + k] * lds[OFF_Z + k];
        }
        sum += __shfl_xor(sum, 1);
        sum += __shfl_xor(sum, 2);
        sum += __shfl_xor(sum, 4);
        if (s == 0) lds[OFF_T1 + i] = sum;
      }
      if (tid == 0) lds[OFF_MISC + 2] = 1.f;
      __syncthreads();
    } else {
      if (tid < SD) lds[OFF_T1 + tid] = lds[OFF_Z + tid];
      if (tid == 0) lds[OFF_MISC + 2] = 1.f;
      __syncthreads();
    }

    // ---- PCtT = C @ P_pred  [64][128];  + per-step NaN check ----
    {
      const int a0 = ti * 2, i0 = tj * 4;
      float acc[2][4] = {};
      for (int m = 0; m < SD; ++m) {
        float c0 = C[(a0 + 0) * SD + m];
        float c1 = C[(a0 + 1) * SD + m];
        float pv[4];
#pragma unroll
        for (int c = 0; c < 4; ++c) pv[c] = lds[OFF_P + m * PST + i0 + c];
#pragma unroll
        for (int c = 0; c < 4; ++c) { acc[0][c] += c0 * pv[c]; acc[1][c] += c1 * pv[c]; }
      }
#pragma unroll
      for (int r = 0; r < 2; ++r)
#pragma unroll
        for (int c = 0; c < 4; ++c)
          lds[OFF_PCTT + (a0 + r) * PST + i0 + c] = acc[r][c];
      if (tid < OD) {
        float yv = y[(size_t)t * OD + tid];
        if (yv != yv) lds[OFF_MISC + 2] = 0.f;
      }
    }
    __syncthreads();

    // ---- S = C P_pred C^T + R + jit ----
    {
      const int a0 = ti * 2, b0 = tj * 2;
      float acc[2][2] = {};
      for (int k = 0; k < SD; ++k) {
        float c0 = C[(a0 + 0) * SD + k];
        float c1 = C[(a0 + 1) * SD + k];
        float p0 = lds[OFF_PCTT + (b0 + 0) * PST + k];
        float p1 = lds[OFF_PCTT + (b0 + 1) * PST + k];
        acc[0][0] += c0 * p0; acc[0][1] += c0 * p1;
        acc[1][0] += c1 * p0; acc[1][1] += c1 * p1;
      }
#pragma unroll
      for (int r = 0; r < 2; ++r)
#pragma unroll
        for (int c = 0; c < 2; ++c) {
          int a = a0 + r, b = b0 + c;
          lds[OFF_S + a * SST + b] =
              acc[r][c] + R[a * OD + b] + ((a == b) ? 1e-6f : 0.f);
        }
    }
    // ---- innov = y_safe - C z_pred ----
    if (tid < 512) {
      int o = tid >> 3, s = tid & 7;
      float sum = 0.f;
      for (int kk = 0; kk < 16; ++kk) {
        int k = s * 16 + kk;
        sum += C[o * SD + k] * lds[OFF_T1 + k];
      }
      sum += __shfl_xor(sum, 1);
      sum += __shfl_xor(sum, 2);
      sum += __shfl_xor(sum, 4);
      if (s == 0) {
        float yv = y[(size_t)t * OD + o];
        if (yv != yv) yv = 0.f;
        lds[OFF_INNOV + o] = yv - sum;
      }
    }
    __syncthreads();

    // ---- Cholesky S = L L^T, logdet ----
    float logdet_step = 0.f;
    for (int j = 0; j < OD; ++j) {
      float a = lds[OFF_S + j * SST + j];
      float inva = 1.0f / a;
      float irs = rsqrtf(a);
      if (tid == 0) logdet_step += logf(a);
#pragma unroll
      for (int p = 0; p < 4; ++p) {
        int idx = tid + p * NTH;
        int i = idx >> 6, k = idx & 63;
        if (i > j && k > j)
          lds[OFF_S + i * SST + k] -=
              lds[OFF_S + i * SST + j] * lds[OFF_S + k * SST + j] * inva;
        if (k == j && i >= j)
          lds[OFF_L + i * SST + j] = lds[OFF_S + i * SST + j] * irs;
      }
      __syncthreads();
    }
    if (tid == 0) logdet_cur = logdet_step;

    // ---- Linv ----
    if (tid < OD) {
      int c = tid;
      for (int i = 0; i < c; ++i) lds[OFF_LINV + i * SST + c] = 0.f;
      for (int i = c; i < OD; ++i) {
        float s = (i == c) ? 1.f : 0.f;
        for (int j = c; j < i; ++j)
          s -= lds[OFF_L + i * SST + j] * lds[OFF_LINV + j * SST + c];
        lds[OFF_LINV + i * SST + c] = s / lds[OFF_L + i * SST + i];
      }
    }
    __syncthreads();

    // ---- Sinv = Linv^T Linv ----
    {
      const int a0 = ti * 2, b0 = tj * 2;
      float acc[2][2] = {};
      for (int k = 0; k < OD; ++k) {
        float la0 = lds[OFF_LINV + k * SST + a0 + 0];
        float la1 = lds[OFF_LINV + k * SST + a0 + 1];
        float lb0 = lds[OFF_LINV + k * SST + b0 + 0];
        float lb1 = lds[OFF_LINV + k * SST + b0 + 1];
        acc[0][0] += la0 * lb0; acc[0][1] += la0 * lb1;
        acc[1][0] += la1 * lb0; acc[1][1] += la1 * lb1;
      }
#pragma unroll
      for (int r = 0; r < 2; ++r)
#pragma unroll
        for (int c = 0; c < 2; ++c)
          lds[OFF_SINV + (a0 + r) * SST + b0 + c] = acc[r][c];
    }
    __syncthreads();

    // ---- quad partials and KT = Sinv @ PCtT ----
    if (tid < 512) {
      int o = tid >> 3, s = tid & 7;
      float sum = 0.f;
      for (int kk = 0; kk < 8; ++kk) {
        int k = s * 8 + kk;
        sum += lds[OFF_SINV + o * SST + k] * lds[OFF_INNOV + k];
      }
      sum += __shfl_xor(sum, 1);
      sum += __shfl_xor(sum, 2);
      sum += __shfl_xor(sum, 4);
      if (s == 0) lds[OFF_RED + o] = sum * lds[OFF_INNOV + o];
    }
    {
      const int a0 = ti * 2, i0 = tj * 4;
      float acc[2][4] = {};
      for (int b = 0; b < OD; ++b) {
        float s0 = lds[OFF_SINV + (a0 + 0) * SST + b];
        float s1 = lds[OFF_SINV + (a0 + 1) * SST + b];
        float pv[4];
#pragma unroll
        for (int c = 0; c < 4; ++c) pv[c] = lds[OFF_PCTT + b * PST + i0 + c];
#pragma unroll
        for (int c = 0; c < 4; ++c) { acc[0][c] += s0 * pv[c]; acc[1][c] += s1 * pv[c]; }
      }
      __syncthreads();
#pragma unroll
      for (int r = 0; r < 2; ++r)
#pragma unroll
        for (int c = 0; c < 4; ++c)
          lds[OFF_KT + (a0 + r) * PST + i0 + c] = acc[r][c];
    }
    __syncthreads();

    const bool valid = (lds[OFF_MISC + 2] != 0.f);
    // ---- ll increment ----
    if (tid < 64) {
      float q = lds[OFF_RED + tid];
      q += __shfl_xor(q, 1);  q += __shfl_xor(q, 2);  q += __shfl_xor(q, 4);
      q += __shfl_xor(q, 8);  q += __shfl_xor(q, 16); q += __shfl_xor(q, 32);
      if (tid == 0 && valid)
        llacc += -0.5f * (logdet_step + q + OD * LOG2PI_F);
    }
    // ---- z update ----
    {
      int i = tid >> 3, s = tid & 7;
      float sum = 0.f;
      for (int kk = 0; kk < 8; ++kk) {
        int k = s * 8 + kk;
        sum += lds[OFF_KT + k * PST + i] * lds[OFF_INNOV + k];
      }
      sum += __shfl_xor(sum, 1);
      sum += __shfl_xor(sum, 2);
      sum += __shfl_xor(sum, 4);
      if (s == 0) {
        float zi = lds[OFF_T1 + i] + (valid ? sum : 0.f);
        lds[OFF_Z + i] = zi;
        states[(size_t)t * SD + i] = zi;
      }
    }
    // ---- P_u = P_pred - K C P_pred ----
    {
      const int i0 = ti * 4, j0 = tj * 4;
      float acc[4][4] = {};
      for (int a = 0; a < OD; ++a) {
        float kv[4], pv[4];
#pragma unroll
        for (int r = 0; r < 4; ++r) kv[r] = lds[OFF_KT + a * PST + i0 + r];
#pragma unroll
        for (int c = 0; c < 4; ++c) pv[c] = lds[OFF_PCTT + a * PST + j0 + c];
#pragma unroll
        for (int r = 0; r < 4; ++r)
#pragma unroll
          for (int c = 0; c < 4; ++c) acc[r][c] += kv[r] * pv[c];
      }
      if (valid) {
#pragma unroll
        for (int r = 0; r < 4; ++r)
#pragma unroll
          for (int c = 0; c < 4; ++c)
            lds[OFF_P + (i0 + r) * PST + j0 + c] -= acc[r][c];
      }
    }
    __syncthreads();

    // ---- write cov[t], convergence check ----
    {
      float maxd = 0.f;
      float* covt = cov + (size_t)t * SD * SD;
      const float* covp = cov + (size_t)(t - 1) * SD * SD;
#pragma unroll
      for (int p = 0; p < 4; ++p) {
        int idx = tid + p * NTH;
        int base = idx * 4;
        int i = base >> 7, j = base & 127;
        float v0 = lds[OFF_P + i * PST + j + 0];
        float v1 = lds[OFF_P + i * PST + j + 1];
        float v2 = lds[OFF_P + i * PST + j + 2];
        float v3 = lds[OFF_P + i * PST + j + 3];
        covt[base + 0] = v0; covt[base + 1] = v1;
        covt[base + 2] = v2; covt[base + 3] = v3;
        if (t > 0 && !hasNaN) {
          float4 pv = ((const float4*)covp)[idx];
          maxd = fmaxf(maxd, fmaxf(fmaxf(fabsf(v0 - pv.x), fabsf(v1 - pv.y)),
                                   fmaxf(fabsf(v2 - pv.z), fabsf(v3 - pv.w))));
        }
      }
      for (int m = 1; m < 64; m <<= 1) maxd = fmaxf(maxd, __shfl_xor(maxd, m));
      if ((tid & 63) == 0) lds[OFF_RED + (tid >> 6)] = maxd;
    }
    __syncthreads();
    if (tid == 0) {
      float md = 0.f;
      for (int w = 0; w < 16; ++w) md = fmaxf(md, lds[OFF_RED + w]);
      if (t > 0 && !hasNaN && md < FREEZE_TOL) lds[OFF_MISC + 0] = 1.f;
    }
    __syncthreads();
    if (lds[OFF_MISC + 0] != 0.f) { tF = t + 1; break; }
    __syncthreads();
  }

  // ---- export steady-state data for the parallel chunk kernels ----
  if (tid == 0) {
    wsi[0] = tF;
    wsf[WS_LL] = llacc;
    wsf[WS_LOGD] = logdet_cur;
  }
  if (tid < SD) wsf[WS_Z + tid] = lds[OFF_Z + tid];
  if (tF < T) {
    for (int p = 0; p < 8; ++p) {
      int idx = tid + p * NTH;            // 8192 = 64x128
      int a = idx >> 7, i = idx & 127;
      wsf[WS_KT + idx] = lds[OFF_KT + a * PST + i];
    }
    for (int p = 0; p < 4; ++p) {
      int idx = tid + p * NTH;            // 4096 = 64x64
      int a = idx >> 6, b = idx & 63;
      wsf[WS_SINV + idx] = lds[OFF_SINV + a * SST + b];
    }
    // CA = C @ A
    __syncthreads();
    for (int p = 0; p < 16; ++p) {
      int idx = tid + p * NTH;
      lds[OFF_P + (idx >> 7) * PST + (idx & 127)] = A[idx];
    }
    __syncthreads();
    {
      const int a0 = ti * 2, k0 = tj * 4;
      float acc[2][4] = {};
      for (int m = 0; m < SD; ++m) {
        float c0 = C[(a0 + 0) * SD + m];
        float c1 = C[(a0 + 1) * SD + m];
        float av[4];
#pragma unroll
        for (int cc = 0; cc < 4; ++cc) av[cc] = lds[OFF_P + m * PST + k0 + cc];
#pragma unroll
        for (int cc = 0; cc < 4; ++cc) { acc[0][cc] += c0 * av[cc]; acc[1][cc] += c1 * av[cc]; }
      }
#pragma unroll
      for (int rr = 0; rr < 2; ++rr)
#pragma unroll
        for (int cc = 0; cc < 4; ++cc)
          wsf[WS_CA + (a0 + rr) * SD + k0 + cc] = acc[rr][cc];
    }
  }
}

// Parallel frozen-phase recursion: chunk c owns t in [c*LCH, (c+1)*LCH) ∩ [tF, T).
// Warm-up from zero state WARM steps earlier (contraction makes the error < 1e-7);
// exact start when the warm-up window reaches tF.
__launch_bounds__(512, 1)
__global__ void kf_chunk(const float* __restrict__ y, const float* __restrict__ A,
                         const float* __restrict__ wsf, const int* __restrict__ wsi,
                         float* __restrict__ out, int T) {
  __shared__ __align__(16) float zv[SD];
  __shared__ __align__(16) float vv[192];
  __shared__ __align__(16) float yb[2][OD];
  __shared__ float red[8];
  const int tid = (int)threadIdx.x;
  const int c = (int)blockIdx.x;
  const int tF = wsi[0];
  float* states = out;
  float* quad_out = (float*)wsf + WS_QUAD;   // const_cast via cast

  int t_end = (c + 1) * LCH; if (t_end > T) t_end = T;
  int t_begin = c * LCH; if (t_begin < tF) t_begin = tF;
  float qacc = 0.f;

  if (t_begin < t_end) {
    int s0 = t_begin - WARM; if (s0 < tF) s0 = tF;
    const int r = tid >> 1, h = tid & 1;      // phase-1 role (tid<384)
    const int ki = tid >> 2, kq = tid & 3;    // K-role
    const int so = tid >> 3, se = tid & 7;    // Sinv-role

    float G[64];
    if (tid < 384) {
      const float* src = (r < SD) ? (A + r * SD + h * 64)
                                  : (wsf + WS_CA + (r - SD) * SD + h * 64);
#pragma unroll
      for (int k = 0; k < 16; ++k) {
        float4 g4 = ((const float4*)src)[k];
        G[4 * k + 0] = g4.x; G[4 * k + 1] = g4.y;
        G[4 * k + 2] = g4.z; G[4 * k + 3] = g4.w;
      }
    }
    float K[16];
#pragma unroll
    for (int k = 0; k < 16; ++k) K[k] = wsf[WS_KT + (kq * 16 + k) * SD + ki];
    float Sv[8];
#pragma unroll
    for (int k = 0; k < 8; ++k) Sv[k] = wsf[WS_SINV + so * OD + se * 8 + k];

    if (tid < SD) zv[tid] = (s0 == tF) ? wsf[WS_Z + tid] : 0.f;
    if (tid < OD) yb[s0 & 1][tid] = y[(size_t)s0 * OD + tid];
    __syncthreads();

    for (int t = s0; t < t_end; ++t) {
      // phase 1: v = [A; CA] z ; wave 7 prefetches next y
      if (tid < 384) {
        const float* zz = zv + h * 64;
        float sum = 0.f;
#pragma unroll
        for (int k = 0; k < 16; ++k) {
          float4 z4 = ((const float4*)zz)[k];
          sum += G[4 * k + 0] * z4.x + G[4 * k + 1] * z4.y +
                 G[4 * k + 2] * z4.z + G[4 * k + 3] * z4.w;
        }
        sum += __shfl_xor(sum, 1);
        if (h == 0) vv[r] = sum;
      } else if (tid >= 448) {
        int o = tid - 448;
        if (t + 1 < t_end) yb[(t + 1) & 1][o] = y[(size_t)(t + 1) * OD + o];
      }
      __syncthreads();
      const float* ybt = yb[t & 1];
      // phase 2a: z_t = v[:128] + K^T innov, innov = y - v[128:]
      {
        const int a0 = kq * 16;
        float sum = 0.f;
#pragma unroll
        for (int k4 = 0; k4 < 4; ++k4) {
          float4 y4 = ((const float4*)(ybt + a0))[k4];
          float4 v4 = ((const float4*)(vv + SD + a0))[k4];
          sum += K[4 * k4 + 0] * (y4.x - v4.x) + K[4 * k4 + 1] * (y4.y - v4.y) +
                 K[4 * k4 + 2] * (y4.z - v4.z) + K[4 * k4 + 3] * (y4.w - v4.w);
        }
        sum += __shfl_xor(sum, 1);
        sum += __shfl_xor(sum, 2);
        if (kq == 0) {
          float zi = vv[ki] + sum;
          zv[ki] = zi;
          if (t >= t_begin) states[(size_t)t * SD + ki] = zi;
        }
      }
      // phase 2b: quad partial (register-accumulated, no extra reduction)
      if (t >= t_begin) {
        const int b0 = se * 8;
        float sp = 0.f;
#pragma unroll
        for (int k4 = 0; k4 < 2; ++k4) {
          float4 y4 = ((const float4*)(ybt + b0))[k4];
          float4 v4 = ((const float4*)(vv + SD + b0))[k4];
          sp += Sv[4 * k4 + 0] * (y4.x - v4.x) + Sv[4 * k4 + 1] * (y4.y - v4.y) +
                Sv[4 * k4 + 2] * (y4.z - v4.z) + Sv[4 * k4 + 3] * (y4.w - v4.w);
        }
        qacc += sp * (ybt[so] - vv[SD + so]);
      }
      __syncthreads();
    }
  }

  // block reduction of qacc -> quad_out[c] (always written)
  float q = qacc;
  for (int m = 1; m < 64; m <<= 1) q += __shfl_xor(q, m);
  if ((tid & 63) == 0) red[tid >> 6] = q;
  __syncthreads();
  if (tid == 0) {
    float s = 0.f;
    for (int w = 0; w < 8; ++w) s += red[w];
    quad_out[c] = s;
  }
}

// combine ll deterministically
__global__ void kf_ll(const float* __restrict__ wsf, const int* __restrict__ wsi,
                      float* __restrict__ out, int T, int nchunks) {
  if (threadIdx.x == 0 && blockIdx.x == 0) {
    int tF = wsi[0];
    float ll = wsf[WS_LL];
    if (tF < T) {
      float qs = 0.f;
      for (int c = 0; c < nchunks; ++c) qs += wsf[WS_QUAD + c];
      ll += -0.5f * (qs + (float)(T - tF) * (wsf[WS_LOGD] + (float)OD * LOG2PI_F));
    }
    out[(size_t)T * SD + (size_t)T * SD * SD] = ll;
  }
}

// fill cov[t] for t >= tF with steady covariance cov[tF-1]
__global__ void kf_fill(float* __restrict__ cov, const int* __restrict__ ws_tf, int T) {
  int t = (int)blockIdx.x;
  int tF = ws_tf[0];
  if (t < tF) return;
  const float4* src = (const float4*)(cov + (size_t)(tF - 1) * SD * SD);
  float4* dst = (float4*)(cov + (size_t)t * SD * SD);
#pragma unroll
  for (int p = 0; p < 16; ++p) {
    int idx = (int)threadIdx.x + p * 256;
    dst[idx] = src[idx];
  }
}

extern "C" void kernel_launch(void* const* d_in, const int* in_sizes, int n_in,
                              void* d_out, int out_size, void* d_ws, size_t ws_size,
                              hipStream_t stream) {
  const float* y  = (const float*)d_in[0];
  const float* A  = (const float*)d_in[1];
  const float* C  = (const float*)d_in[2];
  const float* Q  = (const float*)d_in[3];
  const float* R  = (const float*)d_in[4];
  const float* z0 = (const float*)d_in[5];
  const float* P0 = (const float*)d_in[6];
  float* out = (float*)d_out;
  int T = in_sizes[0] / OD;
  float* wsf = (float*)d_ws;
  int* wsi = (int*)d_ws;

  size_t ldsBytes = (size_t)LDS_FLOATS * sizeof(float);
  (void)hipFuncSetAttribute((const void*)kf_seq,
                            hipFuncAttributeMaxDynamicSharedMemorySize,
                            (int)ldsBytes);

  kf_seq<<<dim3(1), dim3(NTH), ldsBytes, stream>>>(y, A, C, Q, R, z0, P0, out, T, wsf, wsi);

  int nch = (T + LCH - 1) / LCH;
  kf_chunk<<<dim3(nch), dim3(512), 0, stream>>>(y, A, wsf, wsi, out, T);
  kf_ll<<<dim3(1), dim3(64), 0, stream>>>(wsf, wsi, out, T, nch);

  float* cov = out + (size_t)T * SD;
  kf_fill<<<dim3(T), dim3(256), 0, stream>>>(cov, wsi, T);
}